// Round 3
// baseline (2336.034 us; speedup 1.0000x reference)
//
#include <hip/hip_runtime.h>

#define NTOK 72
#define TOPM 20

typedef __attribute__((ext_vector_type(8))) short s8v;
typedef __attribute__((ext_vector_type(4))) float f4v;
typedef __attribute__((ext_vector_type(4))) unsigned short u16x4;

#define MFMA16(a, b, c) __builtin_amdgcn_mfma_f32_16x16x32_bf16((a), (b), (c), 0, 0, 0)

__device__ __forceinline__ unsigned short f2bf(float f) {
  unsigned int u = __float_as_uint(f);
  unsigned int r = (u + 0x7FFFu + ((u >> 16) & 1u)) >> 16;
  return (unsigned short)r;
}
__device__ __forceinline__ float bf2f(unsigned short s) {
  return __uint_as_float(((unsigned int)s) << 16);
}

// ---------------- weight pack --------------------------------------------
// wq: [L][768][256] bf16, row j768 = h*96 + which*32 + d  (k contiguous)
// wp: [L][256][256] bf16, row n, col k
__global__ void pack_w(const float* __restrict__ qkv_w, const float* __restrict__ proj_w,
                       unsigned short* __restrict__ wq, unsigned short* __restrict__ wp) {
  int idx = blockIdx.x * 256 + threadIdx.x;
  if (idx < 2 * 768 * 256) {
    int k = idx & 255; int rest = idx >> 8; int j = rest % 768; int l = rest / 768;
    int h = j / 96, j96 = j - h * 96;
    int which = j96 >> 5, d = j96 & 31;
    wq[idx] = f2bf(qkv_w[(l * 256 + k) * 768 + which * 256 + h * 32 + d]);
  }
  if (idx < 2 * 256 * 256) {
    int k = idx & 255, n = (idx >> 8) & 255, l = idx >> 16;
    wp[idx] = f2bf(proj_w[(l * 256 + k) * 256 + n]);
  }
}

// ---------------- K2: qkv GEMM per sequence ------------------------------
// qkvbuf chunk layout: [(b-b0)][j768][72] bf16, j768 = h*96 + which*32 + d
// (column-major per seq: MFMA C-frag stores become b64 full-line writes)
__global__ __launch_bounds__(512, 6)
void k_qkv(const float* __restrict__ rf, const float* __restrict__ pos,
           unsigned short* __restrict__ xb,
           const unsigned short* __restrict__ wq,
           const float* __restrict__ qkv_b,
           unsigned short* __restrict__ qkvbuf,
           int layer, int b0)
{
  __shared__ __align__(16) unsigned short xs[80 * 264];
  const int tid = threadIdx.x, w = tid >> 6, l = tid & 63, q4 = l >> 4, l15 = l & 15;
  const int b = blockIdx.x + b0;

  for (int i = tid; i < 80 * 264 / 2; i += 512) ((unsigned int*)xs)[i] = 0u;
  __syncthreads();
  if (layer == 0) {
    const float* rfb = rf + (size_t)b * 18432;
    for (int i = tid; i < 18432; i += 512) {
      int c = i / 72, n = i - c * 72;
      xs[n * 264 + c] = f2bf(rfb[i] + pos[n * 256 + c]);
    }
  } else {
    const unsigned short* xbb = xb + (size_t)b * 18432;
    for (int i = tid; i < 2304; i += 512) {
      int n = i >> 5, c8 = (i & 31) << 3;
      *(s8v*)(xs + n * 264 + c8) = *(const s8v*)(xbb + n * 256 + c8);
    }
  }
  __syncthreads();
  if (layer == 0) {  // persist x for the residual path (coalesced s8v)
    unsigned short* xbb = xb + (size_t)b * 18432;
    for (int i = tid; i < 2304; i += 512) {
      int n = i >> 5, c8 = (i & 31) << 3;
      *(s8v*)(xbb + n * 256 + c8) = *(const s8v*)(xs + n * 264 + c8);
    }
  }

  const unsigned short* wqB = wq + (size_t)layer * 768 * 256;
  unsigned short* qkvS = qkvbuf + (size_t)(b - b0) * 55296;  // 768*72
  for (int pass = 0; pass < 3; ++pass) {
    f4v acc[2][5];
    #pragma unroll
    for (int j = 0; j < 2; ++j)
      #pragma unroll
      for (int mt = 0; mt < 5; ++mt) acc[j][mt] = (f4v){0, 0, 0, 0};
    for (int kk = 0; kk < 8; ++kk) {
      int k0 = kk * 32 + q4 * 8;
      s8v a[5];
      #pragma unroll
      for (int mt = 0; mt < 5; ++mt) a[mt] = *(const s8v*)(xs + (mt * 16 + l15) * 264 + k0);
      #pragma unroll
      for (int j = 0; j < 2; ++j) {
        int jrow = (w + 8 * (pass * 2 + j)) * 16 + l15;
        s8v bf = *(const s8v*)(wqB + jrow * 256 + k0);
        #pragma unroll
        for (int mt = 0; mt < 5; ++mt) acc[j][mt] = MFMA16(a[mt], bf, acc[j][mt]);
      }
    }
    #pragma unroll
    for (int j = 0; j < 2; ++j) {
      int j768 = (w + 8 * (pass * 2 + j)) * 16 + l15;
      int h = j768 / 96, j96 = j768 - h * 96;
      int which = j96 >> 5, d = j96 & 31;
      float bv = qkv_b[layer * 768 + which * 256 + h * 32 + d];
      float sc = (which == 0) ? 0.17677669529663687f : 1.0f;
      unsigned short* dstrow = qkvS + (size_t)j768 * 72;
      #pragma unroll
      for (int mt = 0; mt < 5; ++mt) {
        int tok0 = mt * 16 + q4 * 4;
        if (tok0 < NTOK) {
          u16x4 pk;
          #pragma unroll
          for (int r = 0; r < 4; ++r) pk[r] = f2bf((acc[j][mt][r] + bv) * sc);
          *(u16x4*)(dstrow + tok0) = pk;   // b64; wave fills 36 whole 64B lines
        }
      }
    }
  }
}

// ---------------- K3: attention per (sequence, head) ---------------------
#define SP_S 104
__global__ __launch_bounds__(256, 4)
void k_attn(const unsigned short* __restrict__ qkvbuf, unsigned short* __restrict__ ohbuf,
            int b0)
{
  __shared__ __align__(16) unsigned short qs[80 * 40];   // [tok][d] (pad rows 72..79 = 0)
  __shared__ __align__(16) unsigned short ks[80 * 40];
  __shared__ __align__(16) unsigned short vt[32 * SP_S]; // [d][tok] (cols 72..103 = 0)
  __shared__ __align__(16) unsigned short sp[80 * SP_S]; // scores/P
  __shared__ __align__(16) unsigned short ostage[80 * 32];
  const int tid = threadIdx.x, w = tid >> 6, l = tid & 63, q4 = l >> 4, l15 = l & 15;
  const int bh = blockIdx.x;
  const int b = (bh >> 3) + b0, h = bh & 7;
  const unsigned short* qgq = qkvbuf + (size_t)(bh >> 3) * 55296 + (size_t)h * 96 * 72;
  const unsigned short* qgk = qgq + 32 * 72;
  const unsigned short* qgv = qgq + 64 * 72;

  // zero pad regions (disjoint from staged regions)
  for (int i = tid; i < 160; i += 256) ((unsigned int*)(qs + 72 * 40))[i] = 0u;
  for (int i = tid; i < 160; i += 256) ((unsigned int*)(ks + 72 * 40))[i] = 0u;
  for (int i = tid; i < 512; i += 256) {                 // vt cols 72..103
    int d = i >> 4, c = (i & 15) << 1;
    *(unsigned int*)(vt + d * SP_S + 72 + c) = 0u;
  }
  for (int i = tid; i < 960; i += 256) {                 // sp cols 80..103
    int rr = i / 12, c = (i % 12) << 1;
    *(unsigned int*)(sp + rr * SP_S + 80 + c) = 0u;
  }
  // stage q,k transposed ([d][tok] global -> [tok][d] LDS), u32 global reads
  for (int i = tid; i < 1152; i += 256) {
    int f = i << 1;
    int d = f / 72, tok = f - d * 72;
    unsigned int v = *(const unsigned int*)(qgq + f);
    qs[tok * 40 + d] = (unsigned short)v;
    qs[(tok + 1) * 40 + d] = (unsigned short)(v >> 16);
  }
  for (int i = tid; i < 1152; i += 256) {
    int f = i << 1;
    int d = f / 72, tok = f - d * 72;
    unsigned int v = *(const unsigned int*)(qgk + f);
    ks[tok * 40 + d] = (unsigned short)v;
    ks[(tok + 1) * 40 + d] = (unsigned short)(v >> 16);
  }
  // stage v directly ([d][tok] -> [d][tok]) as b128 (72 = 9*8)
  for (int i = tid; i < 288; i += 256) {
    int d = i / 9, t8 = (i - d * 9) << 3;
    *(s8v*)(vt + d * SP_S + t8) = *(const s8v*)(qgv + d * 72 + t8);
  }
  __syncthreads();

  // scores (q pre-scaled in K2): sp[m][n] bf16; pad k-rows give exact 0
  for (int t = w; t < 25; t += 4) {
    int mt = t / 5, kt = t - mt * 5;
    s8v a  = *(const s8v*)(qs + (mt * 16 + l15) * 40 + q4 * 8);
    s8v bf = *(const s8v*)(ks + (kt * 16 + l15) * 40 + q4 * 8);
    f4v c = MFMA16(a, bf, ((f4v){0, 0, 0, 0}));
    int rowb = mt * 16 + q4 * 4, col = kt * 16 + l15;
    #pragma unroll
    for (int r = 0; r < 4; ++r) sp[(rowb + r) * SP_S + col] = f2bf(c[r]);
  }
  __syncthreads();

  // exact top-20 on bf16 keys (16-bit radix) + softmax; P overwrites scores
  for (int rp = 0; rp < 3; ++rp) {
    int row = rp * 32 + w * 8 + (l >> 3);
    if (row < NTOK) {
      int sub = l & 7;
      float vf[9]; unsigned int key[9];
      #pragma unroll
      for (int i = 0; i < 9; ++i) {
        unsigned int s = sp[row * SP_S + sub * 9 + i];
        vf[i] = bf2f((unsigned short)s);
        unsigned int m = (s >> 15) ? 0xFFFFu : 0x8000u;
        key[i] = s ^ m;
      }
      unsigned int thr = 0u;
      for (int bit = 15; bit >= 0; --bit) {
        unsigned int cand = thr | (1u << bit);
        int cnt = 0;
        #pragma unroll
        for (int i = 0; i < 9; ++i) cnt += (key[i] >= cand) ? 1 : 0;
        cnt += __shfl_xor(cnt, 1);
        cnt += __shfl_xor(cnt, 2);
        cnt += __shfl_xor(cnt, 4);
        if (cnt >= TOPM) thr = cand;
      }
      float mx = vf[0];
      #pragma unroll
      for (int i = 1; i < 9; ++i) mx = fmaxf(mx, vf[i]);
      mx = fmaxf(mx, __shfl_xor(mx, 1));
      mx = fmaxf(mx, __shfl_xor(mx, 2));
      mx = fmaxf(mx, __shfl_xor(mx, 4));
      float ssum = 0.f;
      #pragma unroll
      for (int i = 0; i < 9; ++i) {
        float e = (key[i] >= thr) ? __expf(vf[i] - mx) : 0.f;
        vf[i] = e; ssum += e;
      }
      ssum += __shfl_xor(ssum, 1);
      ssum += __shfl_xor(ssum, 2);
      ssum += __shfl_xor(ssum, 4);
      float inv = 1.f / ssum;
      #pragma unroll
      for (int i = 0; i < 9; ++i) sp[row * SP_S + sub * 9 + i] = f2bf(vf[i] * inv);
    }
  }
  __syncthreads();

  // out_h = P V  (K=96; pads zero) -> ostage[tok][32]
  for (int t = w; t < 10; t += 4) {
    int mt = t >> 1, dt = t & 1;
    f4v acc = (f4v){0, 0, 0, 0};
    #pragma unroll
    for (int kk = 0; kk < 3; ++kk) {
      int k0 = kk * 32 + q4 * 8;
      s8v a  = *(const s8v*)(sp + (mt * 16 + l15) * SP_S + k0);
      s8v bf = *(const s8v*)(vt + (dt * 16 + l15) * SP_S + k0);
      acc = MFMA16(a, bf, acc);
    }
    int rowb = mt * 16 + q4 * 4, d = dt * 16 + l15;
    #pragma unroll
    for (int r = 0; r < 4; ++r) ostage[(rowb + r) * 32 + d] = f2bf(acc[r]);
  }
  __syncthreads();

  // coalesced oh write: 4 threads cover each 64B line fully
  unsigned short* ohb = ohbuf + (size_t)b * 18432 + h * 32;
  for (int i = tid; i < 288; i += 256) {
    int tok = i >> 2, c8 = (i & 3) << 3;
    *(s8v*)(ohb + tok * 256 + c8) = *(const s8v*)(ostage + tok * 32 + c8);
  }
}

// ---------------- K4: proj + residual + LN (+ classifier on last) --------
__global__ __launch_bounds__(512, 4)
void k_proj(const unsigned short* __restrict__ ohbuf, const unsigned short* __restrict__ wp,
            const float* __restrict__ proj_b, const float* __restrict__ ln_g,
            const float* __restrict__ ln_b,
            unsigned short* __restrict__ xb,
            const float* __restrict__ w1, const float* __restrict__ b1,
            const float* __restrict__ w2, const float* __restrict__ b2,
            float* __restrict__ out, int layer, int last)
{
  __shared__ __align__(16) unsigned short os[80 * 264];
  __shared__ float red[160];
  __shared__ float mbuf[256];
  __shared__ float hraw[128];
  const int tid = threadIdx.x, w = tid >> 6, l = tid & 63, q4 = l >> 4, l15 = l & 15;
  const int b = blockIdx.x;

  for (int i = tid; i < 80 * 264 / 2; i += 512) ((unsigned int*)os)[i] = 0u;
  if (tid < 160) red[tid] = 0.f;
  if (tid < 256) mbuf[tid] = 0.f;
  if (tid < 128) hraw[tid] = 0.f;
  __syncthreads();
  const unsigned short* ohb = ohbuf + (size_t)b * 18432;
  for (int i = tid; i < 2304; i += 512) {
    int n = i >> 5, c8 = (i & 31) << 3;
    *(s8v*)(os + n * 264 + c8) = *(const s8v*)(ohb + n * 256 + c8);
  }
  __syncthreads();

  const unsigned short* wpB = wp + (size_t)layer * 65536;
  f4v acc[5][2];
  #pragma unroll
  for (int mt = 0; mt < 5; ++mt) { acc[mt][0] = (f4v){0,0,0,0}; acc[mt][1] = (f4v){0,0,0,0}; }
  for (int kk = 0; kk < 8; ++kk) {
    int k0 = kk * 32 + q4 * 8;
    s8v a[5];
    #pragma unroll
    for (int mt = 0; mt < 5; ++mt) a[mt] = *(const s8v*)(os + (mt * 16 + l15) * 264 + k0);
    #pragma unroll
    for (int j = 0; j < 2; ++j) {
      int nrow = w * 32 + j * 16 + l15;
      s8v bf = *(const s8v*)(wpB + nrow * 256 + k0);
      #pragma unroll
      for (int mt = 0; mt < 5; ++mt) acc[mt][j] = MFMA16(a[mt], bf, acc[mt][j]);
    }
  }

  int c0 = w * 32 + l15, c1 = c0 + 16;
  float pb0 = proj_b[layer * 256 + c0], pb1 = proj_b[layer * 256 + c1];
  const unsigned short* xbb = xb + (size_t)b * 18432;
  #pragma unroll
  for (int mt = 0; mt < 5; ++mt) {
    #pragma unroll
    for (int r = 0; r < 4; ++r) {
      int row = mt * 16 + q4 * 4 + r;
      float z0 = 0.f, z1 = 0.f;
      if (row < NTOK) {
        z0 = bf2f(xbb[row * 256 + c0]) + acc[mt][0][r] + pb0;
        z1 = bf2f(xbb[row * 256 + c1]) + acc[mt][1][r] + pb1;
      }
      acc[mt][0][r] = z0; acc[mt][1][r] = z1;
      float s1 = z0 + z1, s2 = z0 * z0 + z1 * z1;
      s1 += __shfl_xor(s1, 1); s2 += __shfl_xor(s2, 1);
      s1 += __shfl_xor(s1, 2); s2 += __shfl_xor(s2, 2);
      s1 += __shfl_xor(s1, 4); s2 += __shfl_xor(s2, 4);
      s1 += __shfl_xor(s1, 8); s2 += __shfl_xor(s2, 8);
      if (l15 == 0 && row < NTOK) {
        atomicAdd(&red[row * 2], s1);
        atomicAdd(&red[row * 2 + 1], s2);
      }
    }
  }
  __syncthreads();

  float g0 = ln_g[layer * 256 + c0], g1 = ln_g[layer * 256 + c1];
  float be0 = ln_b[layer * 256 + c0], be1 = ln_b[layer * 256 + c1];
  unsigned short* xbw = xb + (size_t)b * 18432;
  float msum0 = 0.f, msum1 = 0.f;
  #pragma unroll
  for (int mt = 0; mt < 5; ++mt) {
    #pragma unroll
    for (int r = 0; r < 4; ++r) {
      int row = mt * 16 + q4 * 4 + r;
      if (row < NTOK) {
        float mu = red[row * 2] * (1.f / 256.f);
        float var = red[row * 2 + 1] * (1.f / 256.f) - mu * mu;
        float rstd = rsqrtf(var + 1e-5f);
        float o0 = (acc[mt][0][r] - mu) * rstd * g0 + be0;
        float o1 = (acc[mt][1][r] - mu) * rstd * g1 + be1;
        if (!last) {
          xbw[row * 256 + c0] = f2bf(o0);
          xbw[row * 256 + c1] = f2bf(o1);
        } else {
          msum0 += o0; msum1 += o1;
        }
      }
    }
  }
  if (last) {
    atomicAdd(&mbuf[c0], msum0);
    atomicAdd(&mbuf[c1], msum1);
    __syncthreads();
    if (tid < 256) mbuf[tid] *= (1.f / 72.f);
    __syncthreads();
    {  // h = mean @ W1: 512 threads = 128 cols x 4 k-quarters
      int col = tid & 127, kq = tid >> 7;
      float s = 0.f;
      for (int k = kq * 64; k < kq * 64 + 64; ++k) s += mbuf[k] * w1[k * 128 + col];
      atomicAdd(&hraw[col], s);
    }
    __syncthreads();
    if (w == 0) {
      float h0 = fmaxf(hraw[l] + b1[l], 0.f);
      float h1 = fmaxf(hraw[l + 64] + b1[l + 64], 0.f);
      float p = h0 * w2[l] + h1 * w2[l + 64];
      p += __shfl_xor(p, 1);  p += __shfl_xor(p, 2);  p += __shfl_xor(p, 4);
      p += __shfl_xor(p, 8);  p += __shfl_xor(p, 16); p += __shfl_xor(p, 32);
      if (l == 0) out[b] = p + b2[0];
    }
  }
}

extern "C" void kernel_launch(void* const* d_in, const int* in_sizes, int n_in,
                              void* d_out, int out_size, void* d_ws, size_t ws_size,
                              hipStream_t stream) {
  const float* rf    = (const float*)d_in[0];
  const float* pos   = (const float*)d_in[1];
  const float* qkvw  = (const float*)d_in[2];
  const float* qkvb  = (const float*)d_in[3];
  const float* projw = (const float*)d_in[4];
  const float* projb = (const float*)d_in[5];
  const float* lng   = (const float*)d_in[6];
  const float* lnb   = (const float*)d_in[7];
  const float* w1    = (const float*)d_in[8];
  const float* b1    = (const float*)d_in[9];
  const float* w2    = (const float*)d_in[10];
  const float* b2    = (const float*)d_in[11];
  float* out = (float*)d_out;

  // ws partition (u16 elements)
  unsigned short* wq  = (unsigned short*)d_ws;          // 2*768*256   = 393216
  unsigned short* wp  = wq + 393216;                    // 2*256*256   = 131072
  unsigned short* xb  = wp + 131072;                    // 1920*72*256 = 35389440
  unsigned short* oh  = xb + 35389440;                  // 1920*72*256 = 35389440
  unsigned short* qkv = oh + 35389440;                  // up to 1920*768*72

  const size_t fixed_bytes = (size_t)(393216 + 131072 + 35389440 + 35389440) * 2;
  const size_t qkv_bytes   = (size_t)1920 * 768 * 72 * 2;
  int nc = 1;
  while (nc < 8 && fixed_bytes + qkv_bytes / nc > ws_size) nc *= 2;
  const int bc = 1920 / nc;

  hipLaunchKernelGGL(pack_w, dim3(1536), dim3(256), 0, stream, qkvw, projw, wq, wp);
  for (int layer = 0; layer < 2; ++layer) {
    for (int c = 0; c < nc; ++c) {
      int b0 = c * bc;
      hipLaunchKernelGGL(k_qkv, dim3(bc), dim3(512), 0, stream,
                         rf, pos, xb, wq, qkvb, qkv, layer, b0);
      hipLaunchKernelGGL(k_attn, dim3(bc * 8), dim3(256), 0, stream, qkv, oh, b0);
    }
    hipLaunchKernelGGL(k_proj, dim3(1920), dim3(512), 0, stream,
                       oh, wp, projb, lng, lnb, xb, w1, b1, w2, b2, out,
                       layer, layer == 1 ? 1 : 0);
  }
}

// Round 4
// 1548.506 us; speedup vs baseline: 1.5086x; 1.5086x over previous
//
#include <hip/hip_runtime.h>

#define NTOK 72
#define TOPM 20
#define GSEQ 4

typedef __attribute__((ext_vector_type(8))) short s8v;
typedef __attribute__((ext_vector_type(4))) float f4v;
typedef __attribute__((ext_vector_type(4))) unsigned short u16x4;

#define MFMA16(a, b, c) __builtin_amdgcn_mfma_f32_16x16x32_bf16((a), (b), (c), 0, 0, 0)

__device__ __forceinline__ unsigned short f2bf(float f) {
  unsigned int u = __float_as_uint(f);
  unsigned int r = (u + 0x7FFFu + ((u >> 16) & 1u)) >> 16;
  return (unsigned short)r;
}
__device__ __forceinline__ float bf2f(unsigned short s) {
  return __uint_as_float(((unsigned int)s) << 16);
}

// ---------------- weight pack --------------------------------------------
// wq: [L][768][256] bf16, row j768 = h*96 + which*32 + d  (k contiguous)
// wp: [L][256][256] bf16, row n, col k;  posb: [72][256] bf16
__global__ void pack_w(const float* __restrict__ qkv_w, const float* __restrict__ proj_w,
                       const float* __restrict__ pos,
                       unsigned short* __restrict__ wq, unsigned short* __restrict__ wp,
                       unsigned short* __restrict__ posb) {
  int idx = blockIdx.x * 256 + threadIdx.x;
  if (idx < 2 * 768 * 256) {
    int k = idx & 255; int rest = idx >> 8; int j = rest % 768; int l = rest / 768;
    int h = j / 96, j96 = j - h * 96;
    int which = j96 >> 5, d = j96 & 31;
    wq[idx] = f2bf(qkv_w[(l * 256 + k) * 768 + which * 256 + h * 32 + d]);
  }
  if (idx < 2 * 256 * 256) {
    int k = idx & 255, n = (idx >> 8) & 255, l = idx >> 16;
    wp[idx] = f2bf(proj_w[(l * 256 + k) * 256 + n]);
  }
  if (idx < 72 * 256) posb[idx] = f2bf(pos[idx]);
}

// ---------------- K2: qkv GEMM, GSEQ seqs per block ----------------------
// qkvbuf chunk layout: [(b-b0)][j768][72] bf16, j768 = h*96 + which*32 + d
__global__ __launch_bounds__(512, 2)
void k_qkv(const float* __restrict__ rf, const unsigned short* __restrict__ posb,
           unsigned short* __restrict__ xb,
           const unsigned short* __restrict__ wq,
           const float* __restrict__ qkv_b,
           unsigned short* __restrict__ qkvbuf,
           int layer, int b0)
{
  __shared__ __align__(16) unsigned short xs[80 * 264];     // 42240 B
  __shared__ __align__(16) unsigned short st[256 * 72];     // 36864 B (dense)
  const int tid = threadIdx.x, w = tid >> 6, l = tid & 63, q4 = l >> 4, l15 = l & 15;

  for (int i = tid; i < 80 * 264 / 2; i += 512) ((unsigned int*)xs)[i] = 0u;
  __syncthreads();

  const unsigned short* wqB = wq + (size_t)layer * 768 * 256;

  for (int g = 0; g < GSEQ; ++g) {
    const int b = blockIdx.x * GSEQ + g + b0;
    // ---- stage x ----
    if (layer == 0) {
      const float* rfb = rf + (size_t)b * 18432;
      for (int i = tid; i < 18432; i += 512) {
        int c = i / 72, n = i - c * 72;
        float v = __builtin_nontemporal_load(rfb + i);
        xs[n * 264 + c] = f2bf(v + bf2f(posb[n * 256 + c]));
      }
    } else {
      const unsigned short* xbb = xb + (size_t)b * 18432;
      for (int i = tid; i < 2304; i += 512) {
        int n = i >> 5, c8 = (i & 31) << 3;
        s8v v = __builtin_nontemporal_load((const s8v*)(xbb + n * 256 + c8));
        *(s8v*)(xs + n * 264 + c8) = v;
      }
    }
    __syncthreads();
    if (layer == 0) {  // persist x for the residual path (full-line NT)
      unsigned short* xbb = xb + (size_t)b * 18432;
      for (int i = tid; i < 2304; i += 512) {
        int n = i >> 5, c8 = (i & 31) << 3;
        __builtin_nontemporal_store(*(const s8v*)(xs + n * 264 + c8), (s8v*)(xbb + n * 256 + c8));
      }
    }

    unsigned short* qkvS = qkvbuf + (size_t)(b - b0) * 55296;
    for (int pass = 0; pass < 3; ++pass) {
      f4v acc[2][5];
      #pragma unroll
      for (int j = 0; j < 2; ++j)
        #pragma unroll
        for (int mt = 0; mt < 5; ++mt) acc[j][mt] = (f4v){0, 0, 0, 0};
      for (int kk = 0; kk < 8; ++kk) {
        int k0 = kk * 32 + q4 * 8;
        s8v a[5];
        #pragma unroll
        for (int mt = 0; mt < 5; ++mt) a[mt] = *(const s8v*)(xs + (mt * 16 + l15) * 264 + k0);
        #pragma unroll
        for (int j = 0; j < 2; ++j) {
          int jrow = pass * 256 + (w + 8 * j) * 16 + l15;
          s8v bf = *(const s8v*)(wqB + jrow * 256 + k0);   // cached: keep L2-resident
          #pragma unroll
          for (int mt = 0; mt < 5; ++mt) acc[j][mt] = MFMA16(a[mt], bf, acc[j][mt]);
        }
      }
      // epilogue -> st (dense [256 local-j][72 tok])
      #pragma unroll
      for (int j = 0; j < 2; ++j) {
        int jl = (w + 8 * j) * 16 + l15;
        int j768 = pass * 256 + jl;
        int h = j768 / 96, j96 = j768 - h * 96;
        int which = j96 >> 5, d = j96 & 31;
        float bv = qkv_b[layer * 768 + which * 256 + h * 32 + d];
        float sc = (which == 0) ? 0.17677669529663687f : 1.0f;
        #pragma unroll
        for (int mt = 0; mt < 5; ++mt) {
          int tok0 = mt * 16 + q4 * 4;
          if (tok0 < NTOK) {
            u16x4 pk;
            #pragma unroll
            for (int r = 0; r < 4; ++r) pk[r] = f2bf((acc[j][mt][r] + bv) * sc);
            *(u16x4*)(st + jl * 72 + tok0) = pk;
          }
        }
      }
      __syncthreads();
      // st -> global, dense b128 full-line NT
      unsigned short* dst = qkvS + pass * 18432;
      for (int i = tid; i < 2304; i += 512)
        __builtin_nontemporal_store(*(const s8v*)(st + i * 8), (s8v*)(dst + i * 8));
      __syncthreads();
    }
  }
}

// ---------------- K3: attention per (sequence, head) ---------------------
#define SP_S 104
__global__ __launch_bounds__(256, 4)
void k_attn(const unsigned short* __restrict__ qkvbuf, unsigned short* __restrict__ ohbuf,
            int b0)
{
  __shared__ __align__(16) unsigned short qs[80 * 40];
  __shared__ __align__(16) unsigned short ks[80 * 40];
  __shared__ __align__(16) unsigned short vt[32 * SP_S];
  __shared__ __align__(16) unsigned short sp[80 * SP_S];
  __shared__ __align__(16) unsigned short ostage[80 * 32];
  const int tid = threadIdx.x, w = tid >> 6, l = tid & 63, q4 = l >> 4, l15 = l & 15;
  const int bh = blockIdx.x;
  const int b = (bh >> 3) + b0, h = bh & 7;
  const unsigned short* qgq = qkvbuf + (size_t)(bh >> 3) * 55296 + (size_t)h * 96 * 72;
  const unsigned short* qgk = qgq + 32 * 72;
  const unsigned short* qgv = qgq + 64 * 72;

  for (int i = tid; i < 160; i += 256) ((unsigned int*)(qs + 72 * 40))[i] = 0u;
  for (int i = tid; i < 160; i += 256) ((unsigned int*)(ks + 72 * 40))[i] = 0u;
  for (int i = tid; i < 512; i += 256) {
    int d = i >> 4, c = (i & 15) << 1;
    *(unsigned int*)(vt + d * SP_S + 72 + c) = 0u;
  }
  for (int i = tid; i < 960; i += 256) {
    int rr = i / 12, c = (i % 12) << 1;
    *(unsigned int*)(sp + rr * SP_S + 80 + c) = 0u;
  }
  for (int i = tid; i < 1152; i += 256) {
    int f = i << 1;
    int d = f / 72, tok = f - d * 72;
    unsigned int v = __builtin_nontemporal_load((const unsigned int*)(qgq + f));
    qs[tok * 40 + d] = (unsigned short)v;
    qs[(tok + 1) * 40 + d] = (unsigned short)(v >> 16);
  }
  for (int i = tid; i < 1152; i += 256) {
    int f = i << 1;
    int d = f / 72, tok = f - d * 72;
    unsigned int v = __builtin_nontemporal_load((const unsigned int*)(qgk + f));
    ks[tok * 40 + d] = (unsigned short)v;
    ks[(tok + 1) * 40 + d] = (unsigned short)(v >> 16);
  }
  for (int i = tid; i < 288; i += 256) {
    int d = i / 9, t8 = (i - d * 9) << 3;
    s8v v = __builtin_nontemporal_load((const s8v*)(qgv + d * 72 + t8));
    *(s8v*)(vt + d * SP_S + t8) = v;
  }
  __syncthreads();

  for (int t = w; t < 25; t += 4) {
    int mt = t / 5, kt = t - mt * 5;
    s8v a  = *(const s8v*)(qs + (mt * 16 + l15) * 40 + q4 * 8);
    s8v bf = *(const s8v*)(ks + (kt * 16 + l15) * 40 + q4 * 8);
    f4v c = MFMA16(a, bf, ((f4v){0, 0, 0, 0}));
    int rowb = mt * 16 + q4 * 4, col = kt * 16 + l15;
    #pragma unroll
    for (int r = 0; r < 4; ++r) sp[(rowb + r) * SP_S + col] = f2bf(c[r]);
  }
  __syncthreads();

  for (int rp = 0; rp < 3; ++rp) {
    int row = rp * 32 + w * 8 + (l >> 3);
    if (row < NTOK) {
      int sub = l & 7;
      float vf[9]; unsigned int key[9];
      #pragma unroll
      for (int i = 0; i < 9; ++i) {
        unsigned int s = sp[row * SP_S + sub * 9 + i];
        vf[i] = bf2f((unsigned short)s);
        unsigned int m = (s >> 15) ? 0xFFFFu : 0x8000u;
        key[i] = s ^ m;
      }
      unsigned int thr = 0u;
      for (int bit = 15; bit >= 0; --bit) {
        unsigned int cand = thr | (1u << bit);
        int cnt = 0;
        #pragma unroll
        for (int i = 0; i < 9; ++i) cnt += (key[i] >= cand) ? 1 : 0;
        cnt += __shfl_xor(cnt, 1);
        cnt += __shfl_xor(cnt, 2);
        cnt += __shfl_xor(cnt, 4);
        if (cnt >= TOPM) thr = cand;
      }
      float mx = vf[0];
      #pragma unroll
      for (int i = 1; i < 9; ++i) mx = fmaxf(mx, vf[i]);
      mx = fmaxf(mx, __shfl_xor(mx, 1));
      mx = fmaxf(mx, __shfl_xor(mx, 2));
      mx = fmaxf(mx, __shfl_xor(mx, 4));
      float ssum = 0.f;
      #pragma unroll
      for (int i = 0; i < 9; ++i) {
        float e = (key[i] >= thr) ? __expf(vf[i] - mx) : 0.f;
        vf[i] = e; ssum += e;
      }
      ssum += __shfl_xor(ssum, 1);
      ssum += __shfl_xor(ssum, 2);
      ssum += __shfl_xor(ssum, 4);
      float inv = 1.f / ssum;
      #pragma unroll
      for (int i = 0; i < 9; ++i) sp[row * SP_S + sub * 9 + i] = f2bf(vf[i] * inv);
    }
  }
  __syncthreads();

  for (int t = w; t < 10; t += 4) {
    int mt = t >> 1, dt = t & 1;
    f4v acc = (f4v){0, 0, 0, 0};
    #pragma unroll
    for (int kk = 0; kk < 3; ++kk) {
      int k0 = kk * 32 + q4 * 8;
      s8v a  = *(const s8v*)(sp + (mt * 16 + l15) * SP_S + k0);
      s8v bf = *(const s8v*)(vt + (dt * 16 + l15) * SP_S + k0);
      acc = MFMA16(a, bf, acc);
    }
    int rowb = mt * 16 + q4 * 4, d = dt * 16 + l15;
    #pragma unroll
    for (int r = 0; r < 4; ++r) ostage[(rowb + r) * 32 + d] = f2bf(acc[r]);
  }
  __syncthreads();

  unsigned short* ohb = ohbuf + (size_t)b * 18432 + h * 32;
  for (int i = tid; i < 288; i += 256) {
    int tok = i >> 2, c8 = (i & 3) << 3;
    __builtin_nontemporal_store(*(const s8v*)(ostage + tok * 32 + c8), (s8v*)(ohb + tok * 256 + c8));
  }
}

// ---------------- K4: proj + residual + LN (+ classifier), GSEQ/block ----
__global__ __launch_bounds__(512, 2)
void k_proj(const unsigned short* __restrict__ ohbuf, const unsigned short* __restrict__ wp,
            const float* __restrict__ proj_b, const float* __restrict__ ln_g,
            const float* __restrict__ ln_b,
            unsigned short* __restrict__ xb,
            const float* __restrict__ w1, const float* __restrict__ b1,
            const float* __restrict__ w2, const float* __restrict__ b2,
            float* __restrict__ out, int layer, int last)
{
  __shared__ __align__(16) unsigned short os[80 * 264];
  __shared__ float red[160];
  __shared__ float mbufs[GSEQ][256];
  __shared__ float hb[GSEQ][128];
  const int tid = threadIdx.x, w = tid >> 6, l = tid & 63, q4 = l >> 4, l15 = l & 15;

  for (int i = tid; i < 80 * 264 / 2; i += 512) ((unsigned int*)os)[i] = 0u;
  for (int i = tid; i < GSEQ * 256; i += 512) ((float*)mbufs)[i] = 0.f;
  if (tid < GSEQ * 128) ((float*)hb)[tid] = 0.f;
  __syncthreads();

  const unsigned short* wpB = wp + (size_t)layer * 65536;
  const int c0 = w * 32 + l15, c1 = c0 + 16;
  const float pb0 = proj_b[layer * 256 + c0], pb1 = proj_b[layer * 256 + c1];
  const float g0 = ln_g[layer * 256 + c0], g1 = ln_g[layer * 256 + c1];
  const float be0 = ln_b[layer * 256 + c0], be1 = ln_b[layer * 256 + c1];

  for (int g = 0; g < GSEQ; ++g) {
    const int b = blockIdx.x * GSEQ + g;
    const unsigned short* ohb = ohbuf + (size_t)b * 18432;
    for (int i = tid; i < 2304; i += 512) {
      int n = i >> 5, c8 = (i & 31) << 3;
      s8v v = __builtin_nontemporal_load((const s8v*)(ohb + n * 256 + c8));
      *(s8v*)(os + n * 264 + c8) = v;
    }
    if (tid < 160) red[tid] = 0.f;
    __syncthreads();

    f4v acc[5][2];
    #pragma unroll
    for (int mt = 0; mt < 5; ++mt) { acc[mt][0] = (f4v){0,0,0,0}; acc[mt][1] = (f4v){0,0,0,0}; }
    for (int kk = 0; kk < 8; ++kk) {
      int k0 = kk * 32 + q4 * 8;
      s8v a[5];
      #pragma unroll
      for (int mt = 0; mt < 5; ++mt) a[mt] = *(const s8v*)(os + (mt * 16 + l15) * 264 + k0);
      #pragma unroll
      for (int j = 0; j < 2; ++j) {
        int nrow = w * 32 + j * 16 + l15;
        s8v bf = *(const s8v*)(wpB + nrow * 256 + k0);
        #pragma unroll
        for (int mt = 0; mt < 5; ++mt) acc[mt][j] = MFMA16(a[mt], bf, acc[mt][j]);
      }
    }

    const unsigned short* xbb = xb + (size_t)b * 18432;
    #pragma unroll
    for (int mt = 0; mt < 5; ++mt) {
      #pragma unroll
      for (int r = 0; r < 4; ++r) {
        int row = mt * 16 + q4 * 4 + r;
        float z0 = 0.f, z1 = 0.f;
        if (row < NTOK) {
          z0 = bf2f(xbb[row * 256 + c0]) + acc[mt][0][r] + pb0;
          z1 = bf2f(xbb[row * 256 + c1]) + acc[mt][1][r] + pb1;
        }
        acc[mt][0][r] = z0; acc[mt][1][r] = z1;
        float s1 = z0 + z1, s2 = z0 * z0 + z1 * z1;
        s1 += __shfl_xor(s1, 1); s2 += __shfl_xor(s2, 1);
        s1 += __shfl_xor(s1, 2); s2 += __shfl_xor(s2, 2);
        s1 += __shfl_xor(s1, 4); s2 += __shfl_xor(s2, 4);
        s1 += __shfl_xor(s1, 8); s2 += __shfl_xor(s2, 8);
        if (l15 == 0 && row < NTOK) {
          atomicAdd(&red[row * 2], s1);
          atomicAdd(&red[row * 2 + 1], s2);
        }
      }
    }
    __syncthreads();

    float msum0 = 0.f, msum1 = 0.f;
    #pragma unroll
    for (int mt = 0; mt < 5; ++mt) {
      #pragma unroll
      for (int r = 0; r < 4; ++r) {
        int row = mt * 16 + q4 * 4 + r;
        if (row < NTOK) {
          float mu = red[row * 2] * (1.f / 256.f);
          float var = red[row * 2 + 1] * (1.f / 256.f) - mu * mu;
          float rstd = rsqrtf(var + 1e-5f);
          float o0 = (acc[mt][0][r] - mu) * rstd * g0 + be0;
          float o1 = (acc[mt][1][r] - mu) * rstd * g1 + be1;
          if (!last) {   // stage normalized x back into os for full-line copy-out
            os[row * 264 + c0] = f2bf(o0);
            os[row * 264 + c1] = f2bf(o1);
          } else {
            msum0 += o0; msum1 += o1;
          }
        }
      }
    }
    if (last) {
      atomicAdd(&mbufs[g][c0], msum0);
      atomicAdd(&mbufs[g][c1], msum1);
    }
    __syncthreads();
    if (!last) {
      unsigned short* xbw = xb + (size_t)b * 18432;
      for (int i = tid; i < 2304; i += 512) {
        int n = i >> 5, c8 = (i & 31) << 3;
        __builtin_nontemporal_store(*(const s8v*)(os + n * 264 + c8), (s8v*)(xbw + n * 256 + c8));
      }
    }
    __syncthreads();
  }

  if (last) {
    // classifier: w1 read ONCE per block, reused across GSEQ seqs
    {
      int col = tid & 127, kq = tid >> 7;   // 4 k-quarters
      float sums[GSEQ];
      #pragma unroll
      for (int g = 0; g < GSEQ; ++g) sums[g] = 0.f;
      for (int k = kq * 64; k < kq * 64 + 64; ++k) {
        float wv = w1[k * 128 + col] * (1.f / 72.f);
        #pragma unroll
        for (int g = 0; g < GSEQ; ++g) sums[g] += mbufs[g][k] * wv;
      }
      #pragma unroll
      for (int g = 0; g < GSEQ; ++g) atomicAdd(&hb[g][col], sums[g]);
    }
    __syncthreads();
    if (w == 0) {
      #pragma unroll
      for (int g = 0; g < GSEQ; ++g) {
        float h0 = fmaxf(hb[g][l] + b1[l], 0.f);
        float h1 = fmaxf(hb[g][l + 64] + b1[l + 64], 0.f);
        float p = h0 * w2[l] + h1 * w2[l + 64];
        p += __shfl_xor(p, 1);  p += __shfl_xor(p, 2);  p += __shfl_xor(p, 4);
        p += __shfl_xor(p, 8);  p += __shfl_xor(p, 16); p += __shfl_xor(p, 32);
        if (l == 0) out[blockIdx.x * GSEQ + g] = p + b2[0];
      }
    }
  }
}

extern "C" void kernel_launch(void* const* d_in, const int* in_sizes, int n_in,
                              void* d_out, int out_size, void* d_ws, size_t ws_size,
                              hipStream_t stream) {
  const float* rf    = (const float*)d_in[0];
  const float* pos   = (const float*)d_in[1];
  const float* qkvw  = (const float*)d_in[2];
  const float* qkvb  = (const float*)d_in[3];
  const float* projw = (const float*)d_in[4];
  const float* projb = (const float*)d_in[5];
  const float* lng   = (const float*)d_in[6];
  const float* lnb   = (const float*)d_in[7];
  const float* w1    = (const float*)d_in[8];
  const float* b1    = (const float*)d_in[9];
  const float* w2    = (const float*)d_in[10];
  const float* b2    = (const float*)d_in[11];
  float* out = (float*)d_out;

  // ws partition (u16 elements)
  unsigned short* wq   = (unsigned short*)d_ws;         // 2*768*256   = 393216
  unsigned short* wp   = wq + 393216;                   // 2*256*256   = 131072
  unsigned short* posb = wp + 131072;                   // 72*256      = 18432
  unsigned short* xb   = posb + 18432;                  // 1920*72*256 = 35389440
  unsigned short* oh   = xb + 35389440;                 // 1920*72*256 = 35389440
  unsigned short* qkv  = oh + 35389440;                 // up to 1920*768*72

  const size_t fixed_bytes = (size_t)(393216 + 131072 + 18432 + 35389440 + 35389440) * 2;
  const size_t qkv_bytes   = (size_t)1920 * 768 * 72 * 2;
  int nc = 1;
  while (nc < 8 && fixed_bytes + qkv_bytes / nc > ws_size) nc *= 2;
  const int bc = 1920 / nc;

  hipLaunchKernelGGL(pack_w, dim3(1536), dim3(256), 0, stream, qkvw, projw, pos, wq, wp, posb);
  for (int layer = 0; layer < 2; ++layer) {
    for (int c = 0; c < nc; ++c) {
      int b0 = c * bc;
      hipLaunchKernelGGL(k_qkv, dim3(bc / GSEQ), dim3(512), 0, stream,
                         rf, posb, xb, wq, qkvb, qkv, layer, b0);
      hipLaunchKernelGGL(k_attn, dim3(bc * 8), dim3(256), 0, stream, qkv, oh, b0);
    }
    hipLaunchKernelGGL(k_proj, dim3(1920 / GSEQ), dim3(512), 0, stream,
                       oh, wp, projb, lng, lnb, xb, w1, b1, w2, b2, out,
                       layer, layer == 1 ? 1 : 0);
  }
}

// Round 5
// 1408.756 us; speedup vs baseline: 1.6582x; 1.0992x over previous
//
#include <hip/hip_runtime.h>

#define NTOK 72
#define TOPM 20
#define GSEQ 4

typedef __attribute__((ext_vector_type(8))) short s8v;
typedef __attribute__((ext_vector_type(4))) float f4v;
typedef __attribute__((ext_vector_type(4))) unsigned short u16x4;

#define MFMA16(a, b, c) __builtin_amdgcn_mfma_f32_16x16x32_bf16((a), (b), (c), 0, 0, 0)

__device__ __forceinline__ unsigned short f2bf(float f) {
  unsigned int u = __float_as_uint(f);
  unsigned int r = (u + 0x7FFFu + ((u >> 16) & 1u)) >> 16;
  return (unsigned short)r;
}
__device__ __forceinline__ float bf2f(unsigned short s) {
  return __uint_as_float(((unsigned int)s) << 16);
}

// ---------------- weight pack --------------------------------------------
// wq: [L][768][256] bf16, row j768 = h*96 + which*32 + d  (k contiguous)
// wp: [L][256][256] bf16, row n, col k;  posb: [72][256] bf16
__global__ void pack_w(const float* __restrict__ qkv_w, const float* __restrict__ proj_w,
                       const float* __restrict__ pos,
                       unsigned short* __restrict__ wq, unsigned short* __restrict__ wp,
                       unsigned short* __restrict__ posb) {
  int idx = blockIdx.x * 256 + threadIdx.x;
  if (idx < 2 * 768 * 256) {
    int k = idx & 255; int rest = idx >> 8; int j = rest % 768; int l = rest / 768;
    int h = j / 96, j96 = j - h * 96;
    int which = j96 >> 5, d = j96 & 31;
    wq[idx] = f2bf(qkv_w[(l * 256 + k) * 768 + which * 256 + h * 32 + d]);
  }
  if (idx < 2 * 256 * 256) {
    int k = idx & 255, n = (idx >> 8) & 255, l = idx >> 16;
    wp[idx] = f2bf(proj_w[(l * 256 + k) * 256 + n]);
  }
  if (idx < 72 * 256) posb[idx] = f2bf(pos[idx]);
}

// ---------------- K2: qkv GEMM, GSEQ seqs per block ----------------------
// qkvbuf chunk layout per seq (55296 u16): [h][which][...]:
//   which 0,1 (q,k): [tok 72][d 32]   (mode-B swapped-operand MFMA output)
//   which 2   (v)  : [d 32][tok 72]
__global__ __launch_bounds__(512, 2)
void k_qkv(const float* __restrict__ rf, const unsigned short* __restrict__ posb,
           unsigned short* __restrict__ xb,
           const unsigned short* __restrict__ wq,
           const float* __restrict__ qkv_b,
           unsigned short* __restrict__ qkvbuf,
           int layer, int b0)
{
  __shared__ __align__(16) unsigned short xs[80 * 264];     // 42240 B
  __shared__ __align__(16) unsigned short st[256 * 72];     // 36864 B (dense)
  const int tid = threadIdx.x, w = tid >> 6, l = tid & 63, q4 = l >> 4, l15 = l & 15;

  for (int i = tid; i < 80 * 264 / 2; i += 512) ((unsigned int*)xs)[i] = 0u;
  __syncthreads();

  const unsigned short* wqB = wq + (size_t)layer * 768 * 256;

  for (int g = 0; g < GSEQ; ++g) {
    const int b = blockIdx.x * GSEQ + g + b0;
    // ---- stage x ----
    if (layer == 0) {
      const float* rfb = rf + (size_t)b * 18432;
      for (int i = tid; i < 18432; i += 512) {
        int c = i / 72, n = i - c * 72;
        float v = __builtin_nontemporal_load(rfb + i);
        xs[n * 264 + c] = f2bf(v + bf2f(posb[n * 256 + c]));
      }
    } else {
      const unsigned short* xbb = xb + (size_t)b * 18432;
      for (int i = tid; i < 2304; i += 512) {
        int n = i >> 5, c8 = (i & 31) << 3;
        s8v v = __builtin_nontemporal_load((const s8v*)(xbb + n * 256 + c8));
        *(s8v*)(xs + n * 264 + c8) = v;
      }
    }
    __syncthreads();
    if (layer == 0) {  // persist x for the residual path (full-line NT)
      unsigned short* xbb = xb + (size_t)b * 18432;
      for (int i = tid; i < 2304; i += 512) {
        int n = i >> 5, c8 = (i & 31) << 3;
        __builtin_nontemporal_store(*(const s8v*)(xs + n * 264 + c8), (s8v*)(xbb + n * 256 + c8));
      }
    }

    unsigned short* qkvS = qkvbuf + (size_t)(b - b0) * 55296;
    for (int pass = 0; pass < 3; ++pass) {
      // per-jj group metadata (wave-uniform)
      int jb[2], j768b[2], hh[2], j96b[2], whg[2];
      #pragma unroll
      for (int jj = 0; jj < 2; ++jj) {
        jb[jj] = (w + 8 * jj) * 16;
        j768b[jj] = pass * 256 + jb[jj];
        hh[jj] = j768b[jj] / 96;
        j96b[jj] = j768b[jj] - hh[jj] * 96;
        whg[jj] = j96b[jj] >> 5;
      }
      f4v acc[2][5];
      #pragma unroll
      for (int jj = 0; jj < 2; ++jj)
        #pragma unroll
        for (int mt = 0; mt < 5; ++mt) acc[jj][mt] = (f4v){0, 0, 0, 0};
      for (int kk = 0; kk < 8; ++kk) {
        int k0 = kk * 32 + q4 * 8;
        s8v a[5];
        #pragma unroll
        for (int mt = 0; mt < 5; ++mt) a[mt] = *(const s8v*)(xs + (mt * 16 + l15) * 264 + k0);
        #pragma unroll
        for (int jj = 0; jj < 2; ++jj) {
          s8v bw = *(const s8v*)(wqB + (j768b[jj] + l15) * 256 + k0);
          if (whg[jj] < 2) {
            // mode B: D[j][tok] -> lane col = tok, rows = d
            #pragma unroll
            for (int mt = 0; mt < 5; ++mt) acc[jj][mt] = MFMA16(bw, a[mt], acc[jj][mt]);
          } else {
            // mode A (v): D[tok][d]
            #pragma unroll
            for (int mt = 0; mt < 5; ++mt) acc[jj][mt] = MFMA16(a[mt], bw, acc[jj][mt]);
          }
        }
      }
      // epilogue -> st (dense, 8 groups x 2304)
      #pragma unroll
      for (int jj = 0; jj < 2; ++jj) {
        int gg = jb[jj] >> 5;
        unsigned short* stg = st + gg * 2304;
        if (whg[jj] < 2) {
          int dloc = (j96b[jj] & 31) + q4 * 4;
          float scl = (whg[jj] == 0) ? 0.17677669529663687f : 1.0f;
          float bv[4];
          #pragma unroll
          for (int r = 0; r < 4; ++r)
            bv[r] = qkv_b[layer * 768 + whg[jj] * 256 + hh[jj] * 32 + dloc + r];
          #pragma unroll
          for (int mt = 0; mt < 5; ++mt) {
            int tok = mt * 16 + l15;
            if (tok < NTOK) {
              u16x4 pk;
              #pragma unroll
              for (int r = 0; r < 4; ++r) pk[r] = f2bf((acc[jj][mt][r] + bv[r]) * scl);
              *(u16x4*)(stg + tok * 32 + dloc) = pk;
            }
          }
        } else {
          int d = (j96b[jj] & 31) + l15;
          float bv = qkv_b[layer * 768 + 512 + hh[jj] * 32 + d];
          #pragma unroll
          for (int mt = 0; mt < 5; ++mt) {
            int tok0 = mt * 16 + q4 * 4;
            if (tok0 < NTOK) {
              u16x4 pk;
              #pragma unroll
              for (int r = 0; r < 4; ++r) pk[r] = f2bf(acc[jj][mt][r] + bv);
              *(u16x4*)(stg + d * 72 + tok0) = pk;
            }
          }
        }
      }
      __syncthreads();
      // st -> global, dense b128 full-line NT
      unsigned short* dst = qkvS + pass * 18432;
      for (int i = tid; i < 2304; i += 512)
        __builtin_nontemporal_store(*(const s8v*)(st + i * 8), (s8v*)(dst + i * 8));
      __syncthreads();
    }
  }
}

// ---------------- K3: attention per (sequence, head) ---------------------
#define SP_S 104
__global__ __launch_bounds__(256, 4)
void k_attn(const unsigned short* __restrict__ qkvbuf, unsigned short* __restrict__ ohbuf,
            int b0)
{
  __shared__ __align__(16) unsigned short qs[80 * 40];   // [tok][d]; aliased as ostage later
  __shared__ __align__(16) unsigned short ks[80 * 40];   // [tok][d]
  __shared__ __align__(16) unsigned short vt[32 * SP_S]; // [d][tok] (cols 72..103 = 0)
  __shared__ __align__(16) unsigned short sp[80 * SP_S]; // scores / P
  unsigned short* ostage = qs;                           // qs dead after score phase
  const int tid = threadIdx.x, w = tid >> 6, l = tid & 63, q4 = l >> 4, l15 = l & 15;
  const int bh = blockIdx.x;
  const int b = (bh >> 3) + b0, h = bh & 7;
  const unsigned short* qgq = qkvbuf + (size_t)(bh >> 3) * 55296 + (size_t)h * 6912;
  const unsigned short* qgk = qgq + 2304;
  const unsigned short* qgv = qgq + 4608;

  // zero pad regions (disjoint from staged regions)
  for (int i = tid; i < 160; i += 256) ((unsigned int*)(qs + 72 * 40))[i] = 0u;
  for (int i = tid; i < 160; i += 256) ((unsigned int*)(ks + 72 * 40))[i] = 0u;
  for (int i = tid; i < 512; i += 256) {                 // vt cols 72..103
    int d = i >> 4, c = (i & 15) << 1;
    *(unsigned int*)(vt + d * SP_S + 72 + c) = 0u;
  }
  for (int i = tid; i < 960; i += 256) {                 // sp cols 80..103
    int rr = i / 12, c = (i % 12) << 1;
    *(unsigned int*)(sp + rr * SP_S + 80 + c) = 0u;
  }
  // stage q,k ([tok][32] -> [tok][40]) and v ([d][72] -> [d][104]), all b128
  for (int i = tid; i < 288; i += 256) {
    int tok = i >> 2, d8 = (i & 3) << 3;
    s8v v = __builtin_nontemporal_load((const s8v*)(qgq + tok * 32 + d8));
    *(s8v*)(qs + tok * 40 + d8) = v;
  }
  for (int i = tid; i < 288; i += 256) {
    int tok = i >> 2, d8 = (i & 3) << 3;
    s8v v = __builtin_nontemporal_load((const s8v*)(qgk + tok * 32 + d8));
    *(s8v*)(ks + tok * 40 + d8) = v;
  }
  for (int i = tid; i < 288; i += 256) {
    int d = i / 9, t8 = (i - d * 9) << 3;
    s8v v = __builtin_nontemporal_load((const s8v*)(qgv + d * 72 + t8));
    *(s8v*)(vt + d * SP_S + t8) = v;
  }
  __syncthreads();

  // scores (q pre-scaled in K2): sp[m][n] bf16; zero k-pad rows give exact 0
  for (int t = w; t < 25; t += 4) {
    int mt = t / 5, kt = t - mt * 5;
    s8v a  = *(const s8v*)(qs + (mt * 16 + l15) * 40 + q4 * 8);
    s8v bf = *(const s8v*)(ks + (kt * 16 + l15) * 40 + q4 * 8);
    f4v c = MFMA16(a, bf, ((f4v){0, 0, 0, 0}));
    int rowb = mt * 16 + q4 * 4, col = kt * 16 + l15;
    #pragma unroll
    for (int r = 0; r < 4; ++r) sp[(rowb + r) * SP_S + col] = f2bf(c[r]);
  }
  __syncthreads();

  // exact top-20 on bf16 keys: ballot-based radix (no LDS swizzles), + softmax
  const int rowsh = l & 56;   // (l>>3)*8 : this row's byte in the wave mask
  for (int rp = 0; rp < 3; ++rp) {
    int row = rp * 32 + w * 8 + (l >> 3);
    if (row < NTOK) {
      int sub = l & 7;
      unsigned short* rowp = sp + row * SP_S;
      s8v raw = *(const s8v*)(rowp + sub * 8);     // cols sub*8 .. +8
      unsigned short uv[9];
      #pragma unroll
      for (int i = 0; i < 8; ++i) uv[i] = (unsigned short)raw[i];
      uv[8] = rowp[64 + sub];                      // col 64+sub
      float vf[9]; unsigned int key[9];
      #pragma unroll
      for (int i = 0; i < 9; ++i) {
        unsigned int s = uv[i];
        vf[i] = bf2f((unsigned short)s);
        key[i] = s ^ ((s >> 15) ? 0xFFFFu : 0x8000u);
      }
      unsigned int thr = 0u;
      for (int bit = 15; bit >= 0; --bit) {
        unsigned int cand = thr | (1u << bit);
        int cnt = 0;
        #pragma unroll
        for (int i = 0; i < 9; ++i) {
          unsigned long long m = __ballot(key[i] >= cand);
          cnt += __popc((unsigned int)(m >> rowsh) & 0xffu);
        }
        if (cnt >= TOPM) thr = cand;
      }
      float mx = vf[0];
      #pragma unroll
      for (int i = 1; i < 9; ++i) mx = fmaxf(mx, vf[i]);
      mx = fmaxf(mx, __shfl_xor(mx, 1));
      mx = fmaxf(mx, __shfl_xor(mx, 2));
      mx = fmaxf(mx, __shfl_xor(mx, 4));
      float ssum = 0.f;
      #pragma unroll
      for (int i = 0; i < 9; ++i) {
        float e = (key[i] >= thr) ? __expf(vf[i] - mx) : 0.f;
        vf[i] = e; ssum += e;
      }
      ssum += __shfl_xor(ssum, 1);
      ssum += __shfl_xor(ssum, 2);
      ssum += __shfl_xor(ssum, 4);
      float inv = 1.f / ssum;
      s8v pout;
      #pragma unroll
      for (int i = 0; i < 8; ++i) pout[i] = (short)f2bf(vf[i] * inv);
      *(s8v*)(rowp + sub * 8) = pout;
      rowp[64 + sub] = f2bf(vf[8] * inv);
    }
  }
  __syncthreads();

  // out_h = P V  (K=96; pads zero) -> ostage[tok][32] (aliases qs)
  for (int t = w; t < 10; t += 4) {
    int mt = t >> 1, dt = t & 1;
    f4v acc = (f4v){0, 0, 0, 0};
    #pragma unroll
    for (int kk = 0; kk < 3; ++kk) {
      int k0 = kk * 32 + q4 * 8;
      s8v a  = *(const s8v*)(sp + (mt * 16 + l15) * SP_S + k0);
      s8v bf = *(const s8v*)(vt + (dt * 16 + l15) * SP_S + k0);
      acc = MFMA16(a, bf, acc);
    }
    int rowb = mt * 16 + q4 * 4, d = dt * 16 + l15;
    #pragma unroll
    for (int r = 0; r < 4; ++r) ostage[(rowb + r) * 32 + d] = f2bf(acc[r]);
  }
  __syncthreads();

  unsigned short* ohb = ohbuf + (size_t)b * 18432 + h * 32;
  for (int i = tid; i < 288; i += 256) {
    int tok = i >> 2, c8 = (i & 3) << 3;
    __builtin_nontemporal_store(*(const s8v*)(ostage + tok * 32 + c8), (s8v*)(ohb + tok * 256 + c8));
  }
}

// ---------------- K4: proj + residual + LN (+ classifier), GSEQ/block ----
__global__ __launch_bounds__(512, 2)
void k_proj(const unsigned short* __restrict__ ohbuf, const unsigned short* __restrict__ wp,
            const float* __restrict__ proj_b, const float* __restrict__ ln_g,
            const float* __restrict__ ln_b,
            unsigned short* __restrict__ xb,
            const float* __restrict__ w1, const float* __restrict__ b1,
            const float* __restrict__ w2, const float* __restrict__ b2,
            float* __restrict__ out, int layer, int last)
{
  __shared__ __align__(16) unsigned short os[80 * 264];
  __shared__ float red[160];
  __shared__ float mbufs[GSEQ][256];
  __shared__ float hb[GSEQ][128];
  const int tid = threadIdx.x, w = tid >> 6, l = tid & 63, q4 = l >> 4, l15 = l & 15;

  for (int i = tid; i < 80 * 264 / 2; i += 512) ((unsigned int*)os)[i] = 0u;
  for (int i = tid; i < GSEQ * 256; i += 512) ((float*)mbufs)[i] = 0.f;
  if (tid < GSEQ * 128) ((float*)hb)[tid] = 0.f;
  __syncthreads();

  const unsigned short* wpB = wp + (size_t)layer * 65536;
  const int c0 = w * 32 + l15, c1 = c0 + 16;
  const float pb0 = proj_b[layer * 256 + c0], pb1 = proj_b[layer * 256 + c1];
  const float g0 = ln_g[layer * 256 + c0], g1 = ln_g[layer * 256 + c1];
  const float be0 = ln_b[layer * 256 + c0], be1 = ln_b[layer * 256 + c1];

  for (int g = 0; g < GSEQ; ++g) {
    const int b = blockIdx.x * GSEQ + g;
    const unsigned short* ohb = ohbuf + (size_t)b * 18432;
    for (int i = tid; i < 2304; i += 512) {
      int n = i >> 5, c8 = (i & 31) << 3;
      s8v v = __builtin_nontemporal_load((const s8v*)(ohb + n * 256 + c8));
      *(s8v*)(os + n * 264 + c8) = v;
    }
    if (tid < 160) red[tid] = 0.f;
    __syncthreads();

    f4v acc[5][2];
    #pragma unroll
    for (int mt = 0; mt < 5; ++mt) { acc[mt][0] = (f4v){0,0,0,0}; acc[mt][1] = (f4v){0,0,0,0}; }
    for (int kk = 0; kk < 8; ++kk) {
      int k0 = kk * 32 + q4 * 8;
      s8v a[5];
      #pragma unroll
      for (int mt = 0; mt < 5; ++mt) a[mt] = *(const s8v*)(os + (mt * 16 + l15) * 264 + k0);
      #pragma unroll
      for (int j = 0; j < 2; ++j) {
        int nrow = w * 32 + j * 16 + l15;
        s8v bf = *(const s8v*)(wpB + nrow * 256 + k0);
        #pragma unroll
        for (int mt = 0; mt < 5; ++mt) acc[mt][j] = MFMA16(a[mt], bf, acc[mt][j]);
      }
    }

    const unsigned short* xbb = xb + (size_t)b * 18432;
    #pragma unroll
    for (int mt = 0; mt < 5; ++mt) {
      #pragma unroll
      for (int r = 0; r < 4; ++r) {
        int row = mt * 16 + q4 * 4 + r;
        float z0 = 0.f, z1 = 0.f;
        if (row < NTOK) {
          z0 = bf2f(xbb[row * 256 + c0]) + acc[mt][0][r] + pb0;
          z1 = bf2f(xbb[row * 256 + c1]) + acc[mt][1][r] + pb1;
        }
        acc[mt][0][r] = z0; acc[mt][1][r] = z1;
        float s1 = z0 + z1, s2 = z0 * z0 + z1 * z1;
        s1 += __shfl_xor(s1, 1); s2 += __shfl_xor(s2, 1);
        s1 += __shfl_xor(s1, 2); s2 += __shfl_xor(s2, 2);
        s1 += __shfl_xor(s1, 4); s2 += __shfl_xor(s2, 4);
        s1 += __shfl_xor(s1, 8); s2 += __shfl_xor(s2, 8);
        if (l15 == 0 && row < NTOK) {
          atomicAdd(&red[row * 2], s1);
          atomicAdd(&red[row * 2 + 1], s2);
        }
      }
    }
    __syncthreads();

    float msum0 = 0.f, msum1 = 0.f;
    #pragma unroll
    for (int mt = 0; mt < 5; ++mt) {
      #pragma unroll
      for (int r = 0; r < 4; ++r) {
        int row = mt * 16 + q4 * 4 + r;
        if (row < NTOK) {
          float mu = red[row * 2] * (1.f / 256.f);
          float var = red[row * 2 + 1] * (1.f / 256.f) - mu * mu;
          float rstd = rsqrtf(var + 1e-5f);
          float o0 = (acc[mt][0][r] - mu) * rstd * g0 + be0;
          float o1 = (acc[mt][1][r] - mu) * rstd * g1 + be1;
          if (!last) {
            os[row * 264 + c0] = f2bf(o0);
            os[row * 264 + c1] = f2bf(o1);
          } else {
            msum0 += o0; msum1 += o1;
          }
        }
      }
    }
    if (last) {
      atomicAdd(&mbufs[g][c0], msum0);
      atomicAdd(&mbufs[g][c1], msum1);
    }
    __syncthreads();
    if (!last) {
      unsigned short* xbw = xb + (size_t)b * 18432;
      for (int i = tid; i < 2304; i += 512) {
        int n = i >> 5, c8 = (i & 31) << 3;
        __builtin_nontemporal_store(*(const s8v*)(os + n * 264 + c8), (s8v*)(xbw + n * 256 + c8));
      }
    }
    __syncthreads();
  }

  if (last) {
    {
      int col = tid & 127, kq = tid >> 7;
      float sums[GSEQ];
      #pragma unroll
      for (int g = 0; g < GSEQ; ++g) sums[g] = 0.f;
      for (int k = kq * 64; k < kq * 64 + 64; ++k) {
        float wv = w1[k * 128 + col] * (1.f / 72.f);
        #pragma unroll
        for (int g = 0; g < GSEQ; ++g) sums[g] += mbufs[g][k] * wv;
      }
      #pragma unroll
      for (int g = 0; g < GSEQ; ++g) atomicAdd(&hb[g][col], sums[g]);
    }
    __syncthreads();
    if (w == 0) {
      #pragma unroll
      for (int g = 0; g < GSEQ; ++g) {
        float h0 = fmaxf(hb[g][l] + b1[l], 0.f);
        float h1 = fmaxf(hb[g][l + 64] + b1[l + 64], 0.f);
        float p = h0 * w2[l] + h1 * w2[l + 64];
        p += __shfl_xor(p, 1);  p += __shfl_xor(p, 2);  p += __shfl_xor(p, 4);
        p += __shfl_xor(p, 8);  p += __shfl_xor(p, 16); p += __shfl_xor(p, 32);
        if (l == 0) out[blockIdx.x * GSEQ + g] = p + b2[0];
      }
    }
  }
}

extern "C" void kernel_launch(void* const* d_in, const int* in_sizes, int n_in,
                              void* d_out, int out_size, void* d_ws, size_t ws_size,
                              hipStream_t stream) {
  const float* rf    = (const float*)d_in[0];
  const float* pos   = (const float*)d_in[1];
  const float* qkvw  = (const float*)d_in[2];
  const float* qkvb  = (const float*)d_in[3];
  const float* projw = (const float*)d_in[4];
  const float* projb = (const float*)d_in[5];
  const float* lng   = (const float*)d_in[6];
  const float* lnb   = (const float*)d_in[7];
  const float* w1    = (const float*)d_in[8];
  const float* b1    = (const float*)d_in[9];
  const float* w2    = (const float*)d_in[10];
  const float* b2    = (const float*)d_in[11];
  float* out = (float*)d_out;

  // ws partition (u16 elements)
  unsigned short* wq   = (unsigned short*)d_ws;         // 2*768*256   = 393216
  unsigned short* wp   = wq + 393216;                   // 2*256*256   = 131072
  unsigned short* posb = wp + 131072;                   // 72*256      = 18432
  unsigned short* xb   = posb + 18432;                  // 1920*72*256 = 35389440
  unsigned short* oh   = xb + 35389440;                 // 1920*72*256 = 35389440
  unsigned short* qkv  = oh + 35389440;                 // up to 1920*768*72

  const size_t fixed_bytes = (size_t)(393216 + 131072 + 18432 + 35389440 + 35389440) * 2;
  const size_t qkv_bytes   = (size_t)1920 * 768 * 72 * 2;
  int nc = 1;
  while (nc < 8 && fixed_bytes + qkv_bytes / nc > ws_size) nc *= 2;
  const int bc = 1920 / nc;

  hipLaunchKernelGGL(pack_w, dim3(1536), dim3(256), 0, stream, qkvw, projw, pos, wq, wp, posb);
  for (int layer = 0; layer < 2; ++layer) {
    for (int c = 0; c < nc; ++c) {
      int b0 = c * bc;
      hipLaunchKernelGGL(k_qkv, dim3(bc / GSEQ), dim3(512), 0, stream,
                         rf, posb, xb, wq, qkvb, qkv, layer, b0);
      hipLaunchKernelGGL(k_attn, dim3(bc * 8), dim3(256), 0, stream, qkv, oh, b0);
    }
    hipLaunchKernelGGL(k_proj, dim3(1920 / GSEQ), dim3(512), 0, stream,
                       oh, wp, projb, lng, lnb, xb, w1, b1, w2, b2, out,
                       layer, layer == 1 ? 1 : 0);
  }
}

// Round 6
// 1355.042 us; speedup vs baseline: 1.7240x; 1.0396x over previous
//
#include <hip/hip_runtime.h>

#define NTOK 72
#define TOPM 20
#define GSEQ 4

typedef __attribute__((ext_vector_type(8))) short s8v;
typedef __attribute__((ext_vector_type(4))) float f4v;
typedef __attribute__((ext_vector_type(4))) unsigned short u16x4;

#define MFMA16(a, b, c) __builtin_amdgcn_mfma_f32_16x16x32_bf16((a), (b), (c), 0, 0, 0)

__device__ __forceinline__ unsigned short f2bf(float f) {
  unsigned int u = __float_as_uint(f);
  unsigned int r = (u + 0x7FFFu + ((u >> 16) & 1u)) >> 16;
  return (unsigned short)r;
}
__device__ __forceinline__ float bf2f(unsigned short s) {
  return __uint_as_float(((unsigned int)s) << 16);
}

// ---------------- weight pack --------------------------------------------
// wq: [L][768][256] bf16, row j768 = h*96 + which*32 + d  (k contiguous)
// wp: [L][256][256] bf16, row n, col k;  posT: [256 c][72 n] bf16 (transposed!)
__global__ void pack_w(const float* __restrict__ qkv_w, const float* __restrict__ proj_w,
                       const float* __restrict__ pos,
                       unsigned short* __restrict__ wq, unsigned short* __restrict__ wp,
                       unsigned short* __restrict__ posT) {
  int idx = blockIdx.x * 256 + threadIdx.x;
  if (idx < 2 * 768 * 256) {
    int k = idx & 255; int rest = idx >> 8; int j = rest % 768; int l = rest / 768;
    int h = j / 96, j96 = j - h * 96;
    int which = j96 >> 5, d = j96 & 31;
    wq[idx] = f2bf(qkv_w[(l * 256 + k) * 768 + which * 256 + h * 32 + d]);
  }
  if (idx < 2 * 256 * 256) {
    int k = idx & 255, n = (idx >> 8) & 255, l = idx >> 16;
    wp[idx] = f2bf(proj_w[(l * 256 + k) * 256 + n]);
  }
  if (idx < 72 * 256) {
    int c = idx / 72, n = idx - c * 72;
    posT[idx] = f2bf(pos[n * 256 + c]);
  }
}

// ---------------- K2: qkv GEMM, GSEQ seqs per block ----------------------
// qkvbuf chunk layout per seq (55296 u16): [h][which][...]:
//   which 0,1 (q,k): [tok 72][d 32]   (mode-B swapped-operand MFMA output)
//   which 2   (v)  : [d 32][tok 72]
__global__ __launch_bounds__(512, 2)
void k_qkv(const float* __restrict__ rf, const unsigned short* __restrict__ posT,
           unsigned short* __restrict__ xb,
           const unsigned short* __restrict__ wq,
           const float* __restrict__ qkv_b,
           unsigned short* __restrict__ qkvbuf,
           int layer, int b0)
{
  __shared__ __align__(16) unsigned short xs[80 * 264];     // 42240 B (pads never read-live)
  __shared__ __align__(16) unsigned short st[256 * 72];     // 36864 B (dense)
  const int tid = threadIdx.x, w = tid >> 6, l = tid & 63, q4 = l >> 4, l15 = l & 15;

  const unsigned short* wqB = wq + (size_t)layer * 768 * 256;

  for (int g = 0; g < GSEQ; ++g) {
    const int b = blockIdx.x * GSEQ + g + b0;
    // ---- stage x ----
    if (layer == 0) {
      const f4v* rfb4 = (const f4v*)(rf + (size_t)b * 18432);
      for (int i = tid; i < 4608; i += 512) {
        int c = i / 18, n0 = (i - c * 18) * 4;
        f4v v = __builtin_nontemporal_load(rfb4 + i);        // rf streamed, keep NT
        u16x4 p = *(const u16x4*)(posT + i * 4);             // L2-resident
        #pragma unroll
        for (int r = 0; r < 4; ++r)
          xs[(n0 + r) * 264 + c] = f2bf(v[r] + bf2f(p[r]));
      }
    } else {
      const unsigned short* xbb = xb + (size_t)b * 18432;
      for (int i = tid; i < 2304; i += 512) {
        int n = i >> 5, c8 = (i & 31) << 3;
        *(s8v*)(xs + n * 264 + c8) = *(const s8v*)(xbb + n * 256 + c8);  // L3-hot
      }
    }
    __syncthreads();
    if (layer == 0) {  // persist x for the residual path (cached: L3 round-trip)
      unsigned short* xbb = xb + (size_t)b * 18432;
      for (int i = tid; i < 2304; i += 512) {
        int n = i >> 5, c8 = (i & 31) << 3;
        *(s8v*)(xbb + n * 256 + c8) = *(const s8v*)(xs + n * 264 + c8);
      }
    }

    unsigned short* qkvS = qkvbuf + (size_t)(b - b0) * 55296;
    for (int pass = 0; pass < 3; ++pass) {
      // per-jj group metadata (wave-uniform)
      int jb[2], j768b[2], hh[2], j96b[2], whg[2];
      #pragma unroll
      for (int jj = 0; jj < 2; ++jj) {
        jb[jj] = (w + 8 * jj) * 16;
        j768b[jj] = pass * 256 + jb[jj];
        hh[jj] = j768b[jj] / 96;
        j96b[jj] = j768b[jj] - hh[jj] * 96;
        whg[jj] = j96b[jj] >> 5;
      }
      f4v acc[2][5];
      #pragma unroll
      for (int jj = 0; jj < 2; ++jj)
        #pragma unroll
        for (int mt = 0; mt < 5; ++mt) acc[jj][mt] = (f4v){0, 0, 0, 0};
      for (int kk = 0; kk < 8; ++kk) {
        int k0 = kk * 32 + q4 * 8;
        s8v a[5];
        #pragma unroll
        for (int mt = 0; mt < 5; ++mt) a[mt] = *(const s8v*)(xs + (mt * 16 + l15) * 264 + k0);
        #pragma unroll
        for (int jj = 0; jj < 2; ++jj) {
          s8v bw = *(const s8v*)(wqB + (j768b[jj] + l15) * 256 + k0);
          if (whg[jj] < 2) {
            // mode B: D[j][tok] -> lane col = tok, rows = d
            #pragma unroll
            for (int mt = 0; mt < 5; ++mt) acc[jj][mt] = MFMA16(bw, a[mt], acc[jj][mt]);
          } else {
            // mode A (v): D[tok][d]
            #pragma unroll
            for (int mt = 0; mt < 5; ++mt) acc[jj][mt] = MFMA16(a[mt], bw, acc[jj][mt]);
          }
        }
      }
      // epilogue -> st (dense, 8 groups x 2304; fully overwritten each pass)
      #pragma unroll
      for (int jj = 0; jj < 2; ++jj) {
        int gg = jb[jj] >> 5;
        unsigned short* stg = st + gg * 2304;
        if (whg[jj] < 2) {
          int dloc = (j96b[jj] & 31) + q4 * 4;
          float scl = (whg[jj] == 0) ? 0.17677669529663687f : 1.0f;
          float bv[4];
          #pragma unroll
          for (int r = 0; r < 4; ++r)
            bv[r] = qkv_b[layer * 768 + whg[jj] * 256 + hh[jj] * 32 + dloc + r];
          #pragma unroll
          for (int mt = 0; mt < 5; ++mt) {
            int tok = mt * 16 + l15;
            if (tok < NTOK) {
              u16x4 pk;
              #pragma unroll
              for (int r = 0; r < 4; ++r) pk[r] = f2bf((acc[jj][mt][r] + bv[r]) * scl);
              *(u16x4*)(stg + tok * 32 + dloc) = pk;
            }
          }
        } else {
          int d = (j96b[jj] & 31) + l15;
          float bv = qkv_b[layer * 768 + 512 + hh[jj] * 32 + d];
          #pragma unroll
          for (int mt = 0; mt < 5; ++mt) {
            int tok0 = mt * 16 + q4 * 4;
            if (tok0 < NTOK) {
              u16x4 pk;
              #pragma unroll
              for (int r = 0; r < 4; ++r) pk[r] = f2bf(acc[jj][mt][r] + bv);
              *(u16x4*)(stg + d * 72 + tok0) = pk;
            }
          }
        }
      }
      __syncthreads();
      // st -> global, dense b128 full-line CACHED stores (L3 round-trip to k_attn)
      unsigned short* dst = qkvS + pass * 18432;
      for (int i = tid; i < 2304; i += 512)
        *(s8v*)(dst + i * 8) = *(const s8v*)(st + i * 8);
      __syncthreads();
    }
  }
}

// ---------------- K3: attention per (sequence, head) ---------------------
#define SP_S 104
__global__ __launch_bounds__(256, 4)
void k_attn(const unsigned short* __restrict__ qkvbuf, unsigned short* __restrict__ ohbuf,
            int b0)
{
  __shared__ __align__(16) unsigned short qs[80 * 40];   // [tok][d]; aliased as ostage later
  __shared__ __align__(16) unsigned short ks[80 * 40];   // [tok][d]
  __shared__ __align__(16) unsigned short vt[32 * SP_S]; // [d][tok] (cols 72..103 = 0)
  __shared__ __align__(16) unsigned short sp[80 * SP_S]; // scores / P
  unsigned short* ostage = qs;                           // qs dead after score phase
  const int tid = threadIdx.x, w = tid >> 6, l = tid & 63, q4 = l >> 4, l15 = l & 15;
  const int bh = blockIdx.x;
  const int b = (bh >> 3) + b0, h = bh & 7;
  const unsigned short* qgq = qkvbuf + (size_t)(bh >> 3) * 55296 + (size_t)h * 6912;
  const unsigned short* qgk = qgq + 2304;
  const unsigned short* qgv = qgq + 4608;

  // zero pad regions (disjoint from staged regions)
  for (int i = tid; i < 160; i += 256) ((unsigned int*)(ks + 72 * 40))[i] = 0u;
  for (int i = tid; i < 512; i += 256) {                 // vt cols 72..103
    int d = i >> 4, c = (i & 15) << 1;
    *(unsigned int*)(vt + d * SP_S + 72 + c) = 0u;
  }
  for (int i = tid; i < 960; i += 256) {                 // sp cols 80..103
    int rr = i / 12, c = (i % 12) << 1;
    *(unsigned int*)(sp + rr * SP_S + 80 + c) = 0u;
  }
  // stage q,k ([tok][32] -> [tok][40]) and v ([d][72] -> [d][104]), all b128 cached
  for (int i = tid; i < 288; i += 256) {
    int tok = i >> 2, d8 = (i & 3) << 3;
    *(s8v*)(qs + tok * 40 + d8) = *(const s8v*)(qgq + tok * 32 + d8);
  }
  for (int i = tid; i < 288; i += 256) {
    int tok = i >> 2, d8 = (i & 3) << 3;
    *(s8v*)(ks + tok * 40 + d8) = *(const s8v*)(qgk + tok * 32 + d8);
  }
  for (int i = tid; i < 288; i += 256) {
    int d = i / 9, t8 = (i - d * 9) << 3;
    *(s8v*)(vt + d * SP_S + t8) = *(const s8v*)(qgv + d * 72 + t8);
  }
  __syncthreads();

  // scores (q pre-scaled in K2): sp[m][n] bf16; zero k-pad rows give exact 0
  for (int t = w; t < 25; t += 4) {
    int mt = t / 5, kt = t - mt * 5;
    s8v a  = *(const s8v*)(qs + (mt * 16 + l15) * 40 + q4 * 8);
    s8v bf = *(const s8v*)(ks + (kt * 16 + l15) * 40 + q4 * 8);
    f4v c = MFMA16(a, bf, ((f4v){0, 0, 0, 0}));
    int rowb = mt * 16 + q4 * 4, col = kt * 16 + l15;
    #pragma unroll
    for (int r = 0; r < 4; ++r) sp[(rowb + r) * SP_S + col] = f2bf(c[r]);
  }
  __syncthreads();

  // exact top-20 on bf16 keys: ballot-based radix (no LDS swizzles), + softmax
  const int rowsh = l & 56;   // (l>>3)*8 : this row's byte in the wave mask
  for (int rp = 0; rp < 3; ++rp) {
    int row = rp * 32 + w * 8 + (l >> 3);
    if (row < NTOK) {
      int sub = l & 7;
      unsigned short* rowp = sp + row * SP_S;
      s8v raw = *(const s8v*)(rowp + sub * 8);     // cols sub*8 .. +8
      unsigned short uv[9];
      #pragma unroll
      for (int i = 0; i < 8; ++i) uv[i] = (unsigned short)raw[i];
      uv[8] = rowp[64 + sub];                      // col 64+sub
      float vf[9]; unsigned int key[9];
      #pragma unroll
      for (int i = 0; i < 9; ++i) {
        unsigned int s = uv[i];
        vf[i] = bf2f((unsigned short)s);
        key[i] = s ^ ((s >> 15) ? 0xFFFFu : 0x8000u);
      }
      unsigned int thr = 0u;
      for (int bit = 15; bit >= 0; --bit) {
        unsigned int cand = thr | (1u << bit);
        int cnt = 0;
        #pragma unroll
        for (int i = 0; i < 9; ++i) {
          unsigned long long m = __ballot(key[i] >= cand);
          cnt += __popc((unsigned int)(m >> rowsh) & 0xffu);
        }
        if (cnt >= TOPM) thr = cand;
      }
      float mx = vf[0];
      #pragma unroll
      for (int i = 1; i < 9; ++i) mx = fmaxf(mx, vf[i]);
      mx = fmaxf(mx, __shfl_xor(mx, 1));
      mx = fmaxf(mx, __shfl_xor(mx, 2));
      mx = fmaxf(mx, __shfl_xor(mx, 4));
      float ssum = 0.f;
      #pragma unroll
      for (int i = 0; i < 9; ++i) {
        float e = (key[i] >= thr) ? __expf(vf[i] - mx) : 0.f;
        vf[i] = e; ssum += e;
      }
      ssum += __shfl_xor(ssum, 1);
      ssum += __shfl_xor(ssum, 2);
      ssum += __shfl_xor(ssum, 4);
      float inv = 1.f / ssum;
      s8v pout;
      #pragma unroll
      for (int i = 0; i < 8; ++i) pout[i] = (short)f2bf(vf[i] * inv);
      *(s8v*)(rowp + sub * 8) = pout;
      rowp[64 + sub] = f2bf(vf[8] * inv);
    }
  }
  __syncthreads();

  // out_h = P V  (K=96; pads zero) -> ostage[tok][32] (aliases qs)
  for (int t = w; t < 10; t += 4) {
    int mt = t >> 1, dt = t & 1;
    f4v acc = (f4v){0, 0, 0, 0};
    #pragma unroll
    for (int kk = 0; kk < 3; ++kk) {
      int k0 = kk * 32 + q4 * 8;
      s8v a  = *(const s8v*)(sp + (mt * 16 + l15) * SP_S + k0);
      s8v bf = *(const s8v*)(vt + (dt * 16 + l15) * SP_S + k0);
      acc = MFMA16(a, bf, acc);
    }
    int rowb = mt * 16 + q4 * 4, d = dt * 16 + l15;
    #pragma unroll
    for (int r = 0; r < 4; ++r) ostage[(rowb + r) * 32 + d] = f2bf(acc[r]);
  }
  __syncthreads();

  unsigned short* ohb = ohbuf + (size_t)b * 18432 + h * 32;
  for (int i = tid; i < 288; i += 256) {
    int tok = i >> 2, c8 = (i & 3) << 3;
    *(s8v*)(ohb + tok * 256 + c8) = *(const s8v*)(ostage + tok * 32 + c8);
  }
}

// ---------------- K4: proj + residual + LN (+ classifier), GSEQ/block ----
__global__ __launch_bounds__(512, 2)
void k_proj(const unsigned short* __restrict__ ohbuf, const unsigned short* __restrict__ wp,
            const float* __restrict__ proj_b, const float* __restrict__ ln_g,
            const float* __restrict__ ln_b,
            unsigned short* __restrict__ xb,
            const float* __restrict__ w1, const float* __restrict__ b1,
            const float* __restrict__ w2, const float* __restrict__ b2,
            float* __restrict__ out, int layer, int last)
{
  __shared__ __align__(16) unsigned short os[80 * 264];
  __shared__ float red[160];
  __shared__ float mbufs[GSEQ][256];
  __shared__ float hb[GSEQ][128];
  const int tid = threadIdx.x, w = tid >> 6, l = tid & 63, q4 = l >> 4, l15 = l & 15;

  for (int i = tid; i < GSEQ * 256; i += 512) ((float*)mbufs)[i] = 0.f;
  if (tid < GSEQ * 128) ((float*)hb)[tid] = 0.f;

  const unsigned short* wpB = wp + (size_t)layer * 65536;
  const int c0 = w * 32 + l15, c1 = c0 + 16;
  const float pb0 = proj_b[layer * 256 + c0], pb1 = proj_b[layer * 256 + c1];
  const float g0 = ln_g[layer * 256 + c0], g1 = ln_g[layer * 256 + c1];
  const float be0 = ln_b[layer * 256 + c0], be1 = ln_b[layer * 256 + c1];

  for (int g = 0; g < GSEQ; ++g) {
    const int b = blockIdx.x * GSEQ + g;
    const unsigned short* ohb = ohbuf + (size_t)b * 18432;
    for (int i = tid; i < 2304; i += 512) {
      int n = i >> 5, c8 = (i & 31) << 3;
      *(s8v*)(os + n * 264 + c8) = *(const s8v*)(ohb + n * 256 + c8);
    }
    if (tid < 160) red[tid] = 0.f;
    __syncthreads();

    f4v acc[5][2];
    #pragma unroll
    for (int mt = 0; mt < 5; ++mt) { acc[mt][0] = (f4v){0,0,0,0}; acc[mt][1] = (f4v){0,0,0,0}; }
    for (int kk = 0; kk < 8; ++kk) {
      int k0 = kk * 32 + q4 * 8;
      s8v a[5];
      #pragma unroll
      for (int mt = 0; mt < 5; ++mt) a[mt] = *(const s8v*)(os + (mt * 16 + l15) * 264 + k0);
      #pragma unroll
      for (int j = 0; j < 2; ++j) {
        int nrow = w * 32 + j * 16 + l15;
        s8v bf = *(const s8v*)(wpB + nrow * 256 + k0);
        #pragma unroll
        for (int mt = 0; mt < 5; ++mt) acc[mt][j] = MFMA16(a[mt], bf, acc[mt][j]);
      }
    }

    const unsigned short* xbb = xb + (size_t)b * 18432;
    #pragma unroll
    for (int mt = 0; mt < 5; ++mt) {
      #pragma unroll
      for (int r = 0; r < 4; ++r) {
        int row = mt * 16 + q4 * 4 + r;
        float z0 = 0.f, z1 = 0.f;
        if (row < NTOK) {
          z0 = bf2f(xbb[row * 256 + c0]) + acc[mt][0][r] + pb0;
          z1 = bf2f(xbb[row * 256 + c1]) + acc[mt][1][r] + pb1;
        }
        acc[mt][0][r] = z0; acc[mt][1][r] = z1;
        float s1 = z0 + z1, s2 = z0 * z0 + z1 * z1;
        s1 += __shfl_xor(s1, 1); s2 += __shfl_xor(s2, 1);
        s1 += __shfl_xor(s1, 2); s2 += __shfl_xor(s2, 2);
        s1 += __shfl_xor(s1, 4); s2 += __shfl_xor(s2, 4);
        s1 += __shfl_xor(s1, 8); s2 += __shfl_xor(s2, 8);
        if (l15 == 0 && row < NTOK) {
          atomicAdd(&red[row * 2], s1);
          atomicAdd(&red[row * 2 + 1], s2);
        }
      }
    }
    __syncthreads();

    float msum0 = 0.f, msum1 = 0.f;
    #pragma unroll
    for (int mt = 0; mt < 5; ++mt) {
      #pragma unroll
      for (int r = 0; r < 4; ++r) {
        int row = mt * 16 + q4 * 4 + r;
        if (row < NTOK) {
          float mu = red[row * 2] * (1.f / 256.f);
          float var = red[row * 2 + 1] * (1.f / 256.f) - mu * mu;
          float rstd = rsqrtf(var + 1e-5f);
          float o0 = (acc[mt][0][r] - mu) * rstd * g0 + be0;
          float o1 = (acc[mt][1][r] - mu) * rstd * g1 + be1;
          if (!last) {
            os[row * 264 + c0] = f2bf(o0);
            os[row * 264 + c1] = f2bf(o1);
          } else {
            msum0 += o0; msum1 += o1;
          }
        }
      }
    }
    if (last) {
      atomicAdd(&mbufs[g][c0], msum0);
      atomicAdd(&mbufs[g][c1], msum1);
    }
    __syncthreads();
    if (!last) {
      unsigned short* xbw = xb + (size_t)b * 18432;
      for (int i = tid; i < 2304; i += 512) {
        int n = i >> 5, c8 = (i & 31) << 3;
        *(s8v*)(xbw + n * 256 + c8) = *(const s8v*)(os + n * 264 + c8);
      }
    }
    __syncthreads();
  }

  if (last) {
    {
      int col = tid & 127, kq = tid >> 7;
      float sums[GSEQ];
      #pragma unroll
      for (int g = 0; g < GSEQ; ++g) sums[g] = 0.f;
      for (int k = kq * 64; k < kq * 64 + 64; ++k) {
        float wv = w1[k * 128 + col] * (1.f / 72.f);
        #pragma unroll
        for (int g = 0; g < GSEQ; ++g) sums[g] += mbufs[g][k] * wv;
      }
      #pragma unroll
      for (int g = 0; g < GSEQ; ++g) atomicAdd(&hb[g][col], sums[g]);
    }
    __syncthreads();
    if (w == 0) {
      #pragma unroll
      for (int g = 0; g < GSEQ; ++g) {
        float h0 = fmaxf(hb[g][l] + b1[l], 0.f);
        float h1 = fmaxf(hb[g][l + 64] + b1[l + 64], 0.f);
        float p = h0 * w2[l] + h1 * w2[l + 64];
        p += __shfl_xor(p, 1);  p += __shfl_xor(p, 2);  p += __shfl_xor(p, 4);
        p += __shfl_xor(p, 8);  p += __shfl_xor(p, 16); p += __shfl_xor(p, 32);
        if (l == 0) out[blockIdx.x * GSEQ + g] = p + b2[0];
      }
    }
  }
}

extern "C" void kernel_launch(void* const* d_in, const int* in_sizes, int n_in,
                              void* d_out, int out_size, void* d_ws, size_t ws_size,
                              hipStream_t stream) {
  const float* rf    = (const float*)d_in[0];
  const float* pos   = (const float*)d_in[1];
  const float* qkvw  = (const float*)d_in[2];
  const float* qkvb  = (const float*)d_in[3];
  const float* projw = (const float*)d_in[4];
  const float* projb = (const float*)d_in[5];
  const float* lng   = (const float*)d_in[6];
  const float* lnb   = (const float*)d_in[7];
  const float* w1    = (const float*)d_in[8];
  const float* b1    = (const float*)d_in[9];
  const float* w2    = (const float*)d_in[10];
  const float* b2    = (const float*)d_in[11];
  float* out = (float*)d_out;

  // ws partition (u16 elements)
  unsigned short* wq   = (unsigned short*)d_ws;         // 2*768*256   = 393216
  unsigned short* wp   = wq + 393216;                   // 2*256*256   = 131072
  unsigned short* posT = wp + 131072;                   // 72*256      = 18432
  unsigned short* xb   = posT + 18432;                  // 1920*72*256 = 35389440
  unsigned short* oh   = xb + 35389440;                 // 1920*72*256 = 35389440
  unsigned short* qkv  = oh + 35389440;                 // up to 1920*768*72

  const size_t fixed_bytes = (size_t)(393216 + 131072 + 18432 + 35389440 + 35389440) * 2;
  const size_t qkv_bytes   = (size_t)1920 * 768 * 72 * 2;
  int nc = 1;
  while (nc < 8 && fixed_bytes + qkv_bytes / nc > ws_size) nc *= 2;
  const int bc = 1920 / nc;

  hipLaunchKernelGGL(pack_w, dim3(1536), dim3(256), 0, stream, qkvw, projw, pos, wq, wp, posT);
  for (int layer = 0; layer < 2; ++layer) {
    for (int c = 0; c < nc; ++c) {
      int b0 = c * bc;
      hipLaunchKernelGGL(k_qkv, dim3(bc / GSEQ), dim3(512), 0, stream,
                         rf, posT, xb, wq, qkvb, qkv, layer, b0);
      hipLaunchKernelGGL(k_attn, dim3(bc * 8), dim3(256), 0, stream, qkv, oh, b0);
    }
    hipLaunchKernelGGL(k_proj, dim3(1920 / GSEQ), dim3(512), 0, stream,
                       oh, wp, projb, lng, lnb, xb, w1, b1, w2, b2, out,
                       layer, layer == 1 ? 1 : 0);
  }
}